// Round 11
// baseline (261.522 us; speedup 1.0000x reference)
//
#include <hip/hip_runtime.h>
#include <hip/hip_bf16.h>

#define HID 512
#define OD  256
#define HP  513
#define NBLK 1026            /* 131328 rows / 128 per block */
#define EPSV 1e-5f

typedef float f32x4 __attribute__((ext_vector_type(4)));
typedef short s16x8 __attribute__((ext_vector_type(8)));

static __device__ __forceinline__ unsigned short f2bf(float f) {
    union { float f; unsigned u; } x; x.f = f;
    unsigned r = x.u + 0x7FFFu + ((x.u >> 16) & 1u);   // RNE
    return (unsigned short)(r >> 16);
}
static __device__ __forceinline__ unsigned pkbf(float x, float y) {
    float2 t; t.x = x; t.y = y;
    __hip_bfloat162 h = __float22bfloat162_rn(t);
    union { __hip_bfloat162 h; unsigned u; } c; c.h = h;
    return c.u;
}

// permuted k-storage: within a 256-col half, storage s=(ll*8+c) holds true col c*32+ll.
// Applied identically to gpb/bpb/vhT so MFMA contraction pairing stays consistent.

// ---------- prep: gpb/bpb (bf16, permuted), vhT (bf16, permuted), vh512, ahT -
__global__ void prep_all(const float* __restrict__ a, const float* __restrict__ v,
                         const float* __restrict__ gamma, const float* __restrict__ beta,
                         unsigned short* __restrict__ gpb, unsigned short* __restrict__ bpb,
                         unsigned short* __restrict__ vhT, float* __restrict__ vh512,
                         float* __restrict__ ahT) {
    int b = blockIdx.x, t = threadIdx.x;
    if (b < HP) {
        int ii = b;
        for (int s = t; s < 512; s += 256) {
            int half = s >> 8, ss = s & 255, ll = ss >> 3, c = ss & 7;
            int j = half * 256 + c * 32 + ll;
            gpb[(size_t)ii * 512 + s] = f2bf(gamma[(size_t)ii * HP + j]);
            bpb[(size_t)ii * 512 + s] = f2bf(beta [(size_t)ii * HP + j]);
        }
    } else if (b < HP + 128) {
        int m = b - HP;
        for (int s = t; s < 512; s += 256) {
            int half = s >> 8, ss = s & 255, ll = ss >> 3, c = ss & 7;
            int j = half * 256 + c * 32 + ll;
            float val = (j == 0) ? 1.f : v[m * HID + j - 1];
            vhT[(size_t)m * 512 + s] = f2bf(val);
        }
    } else if (b == HP + 128) {
        if (t < 128) vh512[t] = v[t * HID + 511];
    } else {
        int idx = (b - HP - 129) * 256 + t;
        if (idx < HP * 128) {
            int i = idx >> 7, m = idx & 127;
            ahT[idx] = (i == 0) ? 1.f : a[m * HID + i - 1];
        }
    }
}

// ---------- prep2: gather col-512 of W, pre-scaled by gamma/beta -------------
__global__ void prep_w5(const float* __restrict__ W, const float* __restrict__ gamma,
                        const float* __restrict__ beta,
                        float* __restrict__ w5g, float* __restrict__ w5b) {
    int oi = blockIdx.x * 256 + threadIdx.x;
    if (oi < NBLK * 128) {
        unsigned ii = (unsigned)oi % 513u;
        float wv = W[(size_t)oi * 513u + 512u];
        w5g[oi] = gamma[(size_t)ii * HP + 512] * wv;
        w5b[oi] = beta [(size_t)ii * HP + 512] * wv;
    }
}

// ---------- stats ------------------------------------------------------------
__global__ void stats_kernel(const float* __restrict__ a, const float* __restrict__ v,
                             float* __restrict__ mu, float* __restrict__ rsig) {
    __shared__ float s1[256], s2[256], s3[256], s4[256];
    int m = blockIdx.x, t = threadIdx.x;
    float a0 = a[m * HID + t], a1 = a[m * HID + t + 256];
    float v0 = v[m * HID + t], v1 = v[m * HID + t + 256];
    s1[t] = a0 + a1; s2[t] = a0 * a0 + a1 * a1;
    s3[t] = v0 + v1; s4[t] = v0 * v0 + v1 * v1;
    __syncthreads();
    for (int off = 128; off > 0; off >>= 1) {
        if (t < off) { s1[t] += s1[t + off]; s2[t] += s2[t + off];
                       s3[t] += s3[t + off]; s4[t] += s4[t + off]; }
        __syncthreads();
    }
    if (t == 0) {
        float Sa = 1.f + s1[0], Qa = 1.f + s2[0];
        float Sv = 1.f + s3[0], Qv = 1.f + s4[0];
        float muv = Sa * Sv / (float)((float)HP * (float)HP);
        float var = Qa * Qv / (float)((float)HP * (float)HP) - muv * muv;
        mu[m]   = muv;
        rsig[m] = rsqrtf(var + EPSV);
    }
}

// ---------- fused: reg-staged W stream, raw-barrier pipeline, B in LDS -------
// launch_bounds(512,2): LDS (145KB) already forces 1 block/CU = 2 waves/SIMD,
// so declare it -> VGPR cap 256, no spill. 2-deep W/gamma prefetch; beta and
// ah loaded same-body (counted waits leave prefetches in flight); B staged
// once (chunked fill, swizzled); per body: CONV -> A-tile dbuf -> lgkmcnt(0)
// + s_barrier (vmcnt never drained in loop) -> 8 MFMA -> fold per group.
__global__ __launch_bounds__(512, 2) void stage_fused(
        const float* __restrict__ W, const unsigned short* __restrict__ gpb,
        const unsigned short* __restrict__ bpb, const unsigned short* __restrict__ vhT,
        const float* __restrict__ ahT,
        float* __restrict__ Pblk, float* __restrict__ SgPart, float* __restrict__ SbPart) {
    __shared__ __align__(16) char Bs[131072];       // [128][1024B], swizzled
    __shared__ __align__(16) char bt[2][16 * 528];  // A-tile dbuf
    __shared__ float redS[32];

    const int tid = threadIdx.x, lane = tid & 63, w = tid >> 6;
    const int lr = lane & 15, lg = lane >> 4, ll = lane & 31;
    const int cr = 2 * w + (lane >> 5);      // conv row 0..15 (wave-local)
    const int m  = w * 16 + lr;
    const int b = blockIdx.x, gr0 = b * 128;
    const unsigned lo0 = ((unsigned)gr0 / 513u) * 513u;
    const unsigned osw = lo0 + 513u;

    // ---- fill B into LDS (swizzled), chunked: peak 16 VGPR ------------------
#pragma unroll
    for (int q0 = 0; q0 < 16; q0 += 4) {
        uint4 vals[4];
#pragma unroll
        for (int qq = 0; qq < 4; ++qq) {
            int idx = tid + (q0 + qq) * 512;
            int mr = idx >> 6, c = idx & 63;
            vals[qq] = *(const uint4*)(vhT + (size_t)mr * 512 + c * 8);
        }
#pragma unroll
        for (int qq = 0; qq < 4; ++qq) {
            int idx = tid + (q0 + qq) * 512;
            int mr = idx >> 6, c = idx & 63;
            *(uint4*)(&Bs[mr * 1024 + ((c * 16) ^ ((mr & 7) << 4))]) = vals[qq];
        }
    }

    float Wr[2][8];
    uint4 ga[2];
    float ahv[4];
    f32x4 acc = {0.f, 0.f, 0.f, 0.f};
    float psum0 = 0.f, psum1 = 0.f, sg0 = 0.f, sg1 = 0.f, sb0 = 0.f, sb1 = 0.f;

    auto iirow = [&](int t) -> unsigned {
        unsigned oi = (unsigned)(gr0 + (t >> 1) * 16 + cr);
        return oi - (oi >= osw ? osw : lo0);
    };
    auto LOADW = [&](int t, float (&dst)[8]) {
        const float* p = W + (size_t)(gr0 + (t >> 1) * 16 + cr) * 513u + (t & 1) * 256 + ll;
#pragma unroll
        for (int c = 0; c < 8; ++c) dst[c] = p[c * 32];
    };
    auto LOADG = [&](int t) -> uint4 {
        return *(const uint4*)(gpb + (size_t)iirow(t) * 512 + (t & 1) * 256 + ll * 8);
    };
    auto CONV = [&](const float (&Wc)[8], const uint4 gc, const uint4 b4,
                    bool hi_c, char* tile) {
        const unsigned gw[4] = {gc.x, gc.y, gc.z, gc.w};
        float p[8], s = 0.f;
#pragma unroll
        for (int e = 0; e < 8; ++e) {
            unsigned u = (e & 1) ? (gw[e >> 1] >> 16) : (gw[e >> 1] & 0xffffu);
            union { unsigned q; float f; } cv; cv.q = u << 16;
            p[e] = cv.f * Wc[e];
            s += p[e];
        }
        uint4 o4;
        o4.x = pkbf(p[0], p[1]); o4.y = pkbf(p[2], p[3]);
        o4.z = pkbf(p[4], p[5]); o4.w = pkbf(p[6], p[7]);
        *(uint4*)(tile + cr * 528 + ll * 16) = o4;
        const unsigned bw[4] = {b4.x, b4.y, b4.z, b4.w};
        float t2 = 0.f;
#pragma unroll
        for (int e = 0; e < 8; ++e) {
            unsigned u = (e & 1) ? (bw[e >> 1] >> 16) : (bw[e >> 1] & 0xffffu);
            union { unsigned q; float f; } cv; cv.q = u << 16;
            t2 = fmaf(cv.f, Wc[e], t2);
        }
        if (hi_c) { sg1 += s; sb1 += t2; } else { sg0 += s; sb0 += t2; }
    };

    // prologue: 2-deep — issue body 0
    LOADW(0, Wr[0]); ga[0] = LOADG(0);
    __syncthreads();   // B-fill visible (one-time vmcnt drain is acceptable)

#pragma unroll
    for (int t = 0; t < 16; ++t) {
        const int g = t >> 1, half = t & 1;
        const unsigned ii_c = iirow(t);
        const bool hi_c = ((unsigned)(gr0 + g * 16 + cr) >= osw);

        // transient beta(t) — issued FIRST so CONV's counted wait leaves the
        // t+1 prefetches in flight
        uint4 b4 = *(const uint4*)(bpb + (size_t)ii_c * 512 + half * 256 + ll * 8);
        // prefetch W(t+1), gamma(t+1) into the alternate set (2-deep)
        if (t < 15) {
            LOADW(t + 1, Wr[(t + 1) & 1]);
            ga[(t + 1) & 1] = LOADG(t + 1);
        }
        // prefetch ah(g) on even bodies (used at odd-body fold)
        if (half == 0) {
#pragma unroll
            for (int e = 0; e < 4; ++e) {
                unsigned oi = (unsigned)(gr0 + g * 16 + lg * 4 + e);
                unsigned ii = oi - (oi >= osw ? osw : lo0);
                ahv[e] = ahT[(size_t)ii * 128 + m];
            }
        }
        // convert current body (waits only its own W/gamma/beta — counted)
        CONV(Wr[t & 1], ga[t & 1], b4, hi_c, bt[half]);

        // raw barrier: flush LDS writes only; vmcnt stays in flight
        __builtin_amdgcn_sched_barrier(0);
        asm volatile("s_waitcnt lgkmcnt(0)" ::: "memory");
        __builtin_amdgcn_s_barrier();
        __builtin_amdgcn_sched_barrier(0);

        // MFMA: 8 k-slices of this half; A from bt, B from swizzled Bs
#pragma unroll
        for (int ksl = 0; ksl < 8; ++ksl) {
            s16x8 afr = *(const s16x8*)(&bt[half][lr * 528 + ksl * 64 + lg * 16]);
            s16x8 bfrag = *(const s16x8*)(&Bs[m * 1024 +
                            (((half * 512) + ksl * 64 + lg * 16) ^ ((m & 7) << 4))]);
            acc = __builtin_amdgcn_mfma_f32_16x16x32_bf16(afr, bfrag, acc, 0, 0, 0);
        }
        // group fold on odd bodies
        if (half == 1) {
#pragma unroll
            for (int e = 0; e < 4; ++e) {
                unsigned oi = (unsigned)(gr0 + g * 16 + lg * 4 + e);
                float val = acc[e] * ahv[e];
                if (oi >= osw) psum1 += val; else psum0 += val;
            }
            acc = (f32x4){0.f, 0.f, 0.f, 0.f};
        }
    }

    // ---- epilogue ------------------------------------------------------------
    psum0 += __shfl_xor(psum0, 16); psum0 += __shfl_xor(psum0, 32);
    psum1 += __shfl_xor(psum1, 16); psum1 += __shfl_xor(psum1, 32);
    if (lane < 16) {
        Pblk[((size_t)b * 2 + 0) * 128 + m] = psum0;
        Pblk[((size_t)b * 2 + 1) * 128 + m] = psum1;
    }
#pragma unroll
    for (int off = 1; off < 64; off <<= 1) {
        sg0 += __shfl_xor(sg0, off); sg1 += __shfl_xor(sg1, off);
        sb0 += __shfl_xor(sb0, off); sb1 += __shfl_xor(sb1, off);
    }
    if (lane == 0) { redS[w] = sg0; redS[8 + w] = sg1; redS[16 + w] = sb0; redS[24 + w] = sb1; }
    __syncthreads();
    if (tid < 2) {
        float S = 0.f, T = 0.f;
#pragma unroll
        for (int k = 0; k < 8; ++k) { S += redS[tid * 8 + k]; T += redS[16 + tid * 8 + k]; }
        SgPart[b * 2 + tid] = S;
        SbPart[b * 2 + tid] = T;
    }
}

// ---------- finalize: col-512 peel + LN fold + bias + relu -------------------
__global__ void finalize_kernel(const float* __restrict__ Pblk, const float* __restrict__ SgPart,
                                const float* __restrict__ SbPart, const float* __restrict__ w5g,
                                const float* __restrict__ w5b, const float* __restrict__ ahT,
                                const float* __restrict__ vh512, const float* __restrict__ mu,
                                const float* __restrict__ rsig, const float* __restrict__ bias,
                                float* __restrict__ out) {
    __shared__ float wg[HP], wb[HP];
    int o = blockIdx.x, m = threadIdx.x;   // 128 threads
    for (int i = m; i < HP; i += 128) {
        wg[i] = w5g[(size_t)o * HP + i];
        wb[i] = w5b[(size_t)o * HP + i];
    }
    __syncthreads();
    float Pf = 0.f, Sgf = 0.f, Sbf = 0.f;
    for (int i = 0; i < HP; ++i) {
        float g = wg[i];
        Pf = fmaf(ahT[(size_t)i * 128 + m], g, Pf);
        Sgf += g; Sbf += wb[i];
    }
    int b0 = (o * HP) >> 7, b1 = (o * HP + 512) >> 7;
    float P = 0.f, Sg = 0.f, Sb = 0.f;
    for (int bb = b0; bb <= b1; ++bb) {
        unsigned of = ((unsigned)bb * 128u) / 513u;
        int sl = o - (int)of;
        if (sl < 0 || sl > 1) continue;
        P  += Pblk[((size_t)bb * 2 + sl) * 128 + m];
        Sg += SgPart[bb * 2 + sl];
        Sb += SbPart[bb * 2 + sl];
    }
    P += vh512[m] * Pf;
    Sg += Sgf;
    Sb += Sbf;
    float x = rsig[m] * (P - mu[m] * Sg) + Sb + bias[o];
    out[m * OD + o] = fmaxf(x, 0.f);
}

extern "C" void kernel_launch(void* const* d_in, const int* in_sizes, int n_in,
                              void* d_out, int out_size, void* d_ws, size_t ws_size,
                              hipStream_t stream) {
    const float* a     = (const float*)d_in[0];
    const float* v     = (const float*)d_in[1];
    const float* gamma = (const float*)d_in[2];
    const float* beta  = (const float*)d_in[3];
    const float* W     = (const float*)d_in[4];
    const float* bias  = (const float*)d_in[5];
    float* out = (float*)d_out;

    float* cur = (float*)d_ws;
    float* mu     = cur; cur += 128;
    float* rsig   = cur; cur += 128;
    float* SgPart = cur; cur += NBLK * 2;               // 2052
    float* SbPart = cur; cur += NBLK * 2;               // 2052
    float* Pblk   = cur; cur += (size_t)NBLK * 2 * 128; // 262656
    float* ahT    = cur; cur += (size_t)HP * 128;       // 65664
    float* vh512  = cur; cur += 128;
    float* w5g    = cur; cur += (size_t)NBLK * 128;     // 131328
    float* w5b    = cur; cur += (size_t)NBLK * 128;     // 131328
    unsigned short* gpb = (unsigned short*)cur;          // 513*512
    unsigned short* bpb = gpb + (size_t)HP * 512;
    unsigned short* vhT = bpb + (size_t)HP * 512;        // 128*512

    prep_all<<<HP + 128 + 1 + 257, 256, 0, stream>>>(a, v, gamma, beta, gpb, bpb, vhT, vh512, ahT);
    prep_w5<<<HP, 256, 0, stream>>>(W, gamma, beta, w5g, w5b);
    stats_kernel<<<128, 256, 0, stream>>>(a, v, mu, rsig);
    stage_fused<<<NBLK, 512, 0, stream>>>(W, gpb, bpb, vhT, ahT, Pblk, SgPart, SbPart);
    finalize_kernel<<<OD, 128, 0, stream>>>(Pblk, SgPart, SbPart, w5g, w5b, ahT, vh512,
                                            mu, rsig, bias, out);
}

// Round 12
// 138.965 us; speedup vs baseline: 1.8819x; 1.8819x over previous
//
#include <hip/hip_runtime.h>
#include <hip/hip_bf16.h>

#define HID 512
#define OD  256
#define HP  513
#define NBLK 1026            /* 131328 rows / 128 per block */
#define EPSV 1e-5f

typedef float f32x4 __attribute__((ext_vector_type(4)));
typedef short s16x8 __attribute__((ext_vector_type(8)));

static __device__ __forceinline__ unsigned short f2bf(float f) {
    union { float f; unsigned u; } x; x.f = f;
    unsigned r = x.u + 0x7FFFu + ((x.u >> 16) & 1u);   // RNE
    return (unsigned short)(r >> 16);
}
static __device__ __forceinline__ unsigned pkbf(float x, float y) {
    float2 t; t.x = x; t.y = y;
    __hip_bfloat162 h = __float22bfloat162_rn(t);
    union { __hip_bfloat162 h; unsigned u; } c; c.h = h;
    return c.u;
}

// permuted k-storage: within a 256-col half, storage s=(ll*8+c) holds true col c*32+ll.
// Applied identically to gpb/bpb/vhT so MFMA contraction pairing stays consistent.

// ---------- prep: gpb/bpb (bf16, permuted), vhT (bf16, permuted), vh512, ahT -
__global__ void prep_all(const float* __restrict__ a, const float* __restrict__ v,
                         const float* __restrict__ gamma, const float* __restrict__ beta,
                         unsigned short* __restrict__ gpb, unsigned short* __restrict__ bpb,
                         unsigned short* __restrict__ vhT, float* __restrict__ vh512,
                         float* __restrict__ ahT) {
    int b = blockIdx.x, t = threadIdx.x;
    if (b < HP) {
        int ii = b;
        for (int s = t; s < 512; s += 256) {
            int half = s >> 8, ss = s & 255, ll = ss >> 3, c = ss & 7;
            int j = half * 256 + c * 32 + ll;
            gpb[(size_t)ii * 512 + s] = f2bf(gamma[(size_t)ii * HP + j]);
            bpb[(size_t)ii * 512 + s] = f2bf(beta [(size_t)ii * HP + j]);
        }
    } else if (b < HP + 128) {
        int m = b - HP;
        for (int s = t; s < 512; s += 256) {
            int half = s >> 8, ss = s & 255, ll = ss >> 3, c = ss & 7;
            int j = half * 256 + c * 32 + ll;
            float val = (j == 0) ? 1.f : v[m * HID + j - 1];
            vhT[(size_t)m * 512 + s] = f2bf(val);
        }
    } else if (b == HP + 128) {
        if (t < 128) vh512[t] = v[t * HID + 511];
    } else {
        int idx = (b - HP - 129) * 256 + t;
        if (idx < HP * 128) {
            int i = idx >> 7, m = idx & 127;
            ahT[idx] = (i == 0) ? 1.f : a[m * HID + i - 1];
        }
    }
}

// ---------- prep2: gather col-512 of W, pre-scaled by gamma/beta -------------
__global__ void prep_w5(const float* __restrict__ W, const float* __restrict__ gamma,
                        const float* __restrict__ beta,
                        float* __restrict__ w5g, float* __restrict__ w5b) {
    int oi = blockIdx.x * 256 + threadIdx.x;
    if (oi < NBLK * 128) {
        unsigned ii = (unsigned)oi % 513u;
        float wv = W[(size_t)oi * 513u + 512u];
        w5g[oi] = gamma[(size_t)ii * HP + 512] * wv;
        w5b[oi] = beta [(size_t)ii * HP + 512] * wv;
    }
}

// ---------- stats ------------------------------------------------------------
__global__ void stats_kernel(const float* __restrict__ a, const float* __restrict__ v,
                             float* __restrict__ mu, float* __restrict__ rsig) {
    __shared__ float s1[256], s2[256], s3[256], s4[256];
    int m = blockIdx.x, t = threadIdx.x;
    float a0 = a[m * HID + t], a1 = a[m * HID + t + 256];
    float v0 = v[m * HID + t], v1 = v[m * HID + t + 256];
    s1[t] = a0 + a1; s2[t] = a0 * a0 + a1 * a1;
    s3[t] = v0 + v1; s4[t] = v0 * v0 + v1 * v1;
    __syncthreads();
    for (int off = 128; off > 0; off >>= 1) {
        if (t < off) { s1[t] += s1[t + off]; s2[t] += s2[t + off];
                       s3[t] += s3[t + off]; s4[t] += s4[t + off]; }
        __syncthreads();
    }
    if (t == 0) {
        float Sa = 1.f + s1[0], Qa = 1.f + s2[0];
        float Sv = 1.f + s3[0], Qv = 1.f + s4[0];
        float muv = Sa * Sv / (float)((float)HP * (float)HP);
        float var = Qa * Qv / (float)((float)HP * (float)HP) - muv * muv;
        mu[m]   = muv;
        rsig[m] = rsqrtf(var + EPSV);
    }
}

// ---------- fused: rolled 8-group loop, named dual prefetch sets -------------
// Per group g: half0 {beta, prefetch (g,1)->B-set, ah, CONV(A-set), barrier,
// 8 MFMA}; half1 {beta, prefetch (g+1,0)->A-set, CONV(B-set), barrier,
// 8 MFMA, fold}. Barriers drain lgkmcnt only; vmcnt prefetches stay in
// flight. Rolled loop (#pragma unroll 1) keeps live ranges short -> no spill.
__global__ __launch_bounds__(512, 2) void stage_fused(
        const float* __restrict__ W, const unsigned short* __restrict__ gpb,
        const unsigned short* __restrict__ bpb, const unsigned short* __restrict__ vhT,
        const float* __restrict__ ahT,
        float* __restrict__ Pblk, float* __restrict__ SgPart, float* __restrict__ SbPart) {
    __shared__ __align__(16) char Bs[131072];       // [128][1024B], swizzled
    __shared__ __align__(16) char bt[2][16 * 528];  // A-tile dbuf
    __shared__ float redS[32];

    const int tid = threadIdx.x, lane = tid & 63, w = tid >> 6;
    const int lr = lane & 15, lg = lane >> 4, ll = lane & 31;
    const int cr = 2 * w + (lane >> 5);      // conv row 0..15 (wave-local)
    const int m  = w * 16 + lr;
    const int b = blockIdx.x, gr0 = b * 128;
    const unsigned lo0 = ((unsigned)gr0 / 513u) * 513u;
    const unsigned osw = lo0 + 513u;

    // ---- fill B into LDS (swizzled), chunked: peak 16 VGPR ------------------
#pragma unroll
    for (int q0 = 0; q0 < 16; q0 += 4) {
        uint4 vals[4];
#pragma unroll
        for (int qq = 0; qq < 4; ++qq) {
            int idx = tid + (q0 + qq) * 512;
            int mr = idx >> 6, c = idx & 63;
            vals[qq] = *(const uint4*)(vhT + (size_t)mr * 512 + c * 8);
        }
#pragma unroll
        for (int qq = 0; qq < 4; ++qq) {
            int idx = tid + (q0 + qq) * 512;
            int mr = idx >> 6, c = idx & 63;
            *(uint4*)(&Bs[mr * 1024 + ((c * 16) ^ ((mr & 7) << 4))]) = vals[qq];
        }
    }

    float WrA[8], WrB[8];
    uint4 gaA, gaB;
    float ahv[4];
    f32x4 acc = {0.f, 0.f, 0.f, 0.f};
    float psum0 = 0.f, psum1 = 0.f, sg0 = 0.f, sg1 = 0.f, sb0 = 0.f, sb1 = 0.f;

    auto rowii = [&](int g) -> unsigned {
        unsigned oi = (unsigned)(gr0 + g * 16 + cr);
        return oi - (oi >= osw ? osw : lo0);
    };
    auto loadW = [&](int g, int half, float (&dst)[8]) {
        const float* p = W + (size_t)(unsigned)(gr0 + g * 16 + cr) * 513u + half * 256 + ll;
#pragma unroll
        for (int c = 0; c < 8; ++c) dst[c] = p[c * 32];
    };
    auto loadG = [&](unsigned ii, int half) -> uint4 {
        return *(const uint4*)(gpb + ((size_t)ii << 9) + half * 256 + ll * 8);
    };
    auto loadB4 = [&](unsigned ii, int half) -> uint4 {
        return *(const uint4*)(bpb + ((size_t)ii << 9) + half * 256 + ll * 8);
    };
    auto CONV = [&](const float (&Wc)[8], const uint4 gc, const uint4 b4,
                    bool hi_c, char* tile) {
        const unsigned gw[4] = {gc.x, gc.y, gc.z, gc.w};
        float p[8], s = 0.f;
#pragma unroll
        for (int e = 0; e < 8; ++e) {
            unsigned u = (e & 1) ? (gw[e >> 1] >> 16) : (gw[e >> 1] & 0xffffu);
            union { unsigned q; float f; } cv; cv.q = u << 16;
            p[e] = cv.f * Wc[e];
            s += p[e];
        }
        uint4 o4;
        o4.x = pkbf(p[0], p[1]); o4.y = pkbf(p[2], p[3]);
        o4.z = pkbf(p[4], p[5]); o4.w = pkbf(p[6], p[7]);
        *(uint4*)(tile + cr * 528 + ll * 16) = o4;
        const unsigned bw[4] = {b4.x, b4.y, b4.z, b4.w};
        float t2 = 0.f;
#pragma unroll
        for (int e = 0; e < 8; ++e) {
            unsigned u = (e & 1) ? (bw[e >> 1] >> 16) : (bw[e >> 1] & 0xffffu);
            union { unsigned q; float f; } cv; cv.q = u << 16;
            t2 = fmaf(cv.f, Wc[e], t2);
        }
        if (hi_c) { sg1 += s; sb1 += t2; } else { sg0 += s; sb0 += t2; }
    };

    // prologue: issue body (0,0) into A-set
    loadW(0, 0, WrA); gaA = loadG(rowii(0), 0);
    __syncthreads();   // B-fill visible (one-time vmcnt drain is acceptable)

#pragma unroll 1
    for (int g = 0; g < 8; ++g) {
        const unsigned ii = rowii(g);
        const bool hi_c = ((unsigned)(gr0 + g * 16 + cr) >= osw);

        // ================= half 0 =================
        uint4 b40 = loadB4(ii, 0);                  // oldest this body
        loadW(g, 1, WrB); gaB = loadG(ii, 1);       // prefetch (g, half1)
#pragma unroll
        for (int e = 0; e < 4; ++e) {               // ah for this group
            unsigned oi = (unsigned)(gr0 + g * 16 + lg * 4 + e);
            unsigned iie = oi - (oi >= osw ? osw : lo0);
            ahv[e] = ahT[(size_t)iie * 128 + m];
        }
        CONV(WrA, gaA, b40, hi_c, bt[0]);

        __builtin_amdgcn_sched_barrier(0);
        asm volatile("s_waitcnt lgkmcnt(0)" ::: "memory");
        __builtin_amdgcn_s_barrier();
        __builtin_amdgcn_sched_barrier(0);

#pragma unroll
        for (int ksl = 0; ksl < 8; ++ksl) {
            s16x8 afr = *(const s16x8*)(&bt[0][lr * 528 + ksl * 64 + lg * 16]);
            s16x8 bfrag = *(const s16x8*)(&Bs[m * 1024 +
                            ((ksl * 64 + lg * 16) ^ ((m & 7) << 4))]);
            acc = __builtin_amdgcn_mfma_f32_16x16x32_bf16(afr, bfrag, acc, 0, 0, 0);
        }

        // ================= half 1 =================
        uint4 b41 = loadB4(ii, 1);
        if (g < 7) {                                 // prefetch (g+1, half0)
            loadW(g + 1, 0, WrA);
            gaA = loadG(rowii(g + 1), 0);
        }
        CONV(WrB, gaB, b41, hi_c, bt[1]);

        __builtin_amdgcn_sched_barrier(0);
        asm volatile("s_waitcnt lgkmcnt(0)" ::: "memory");
        __builtin_amdgcn_s_barrier();
        __builtin_amdgcn_sched_barrier(0);

#pragma unroll
        for (int ksl = 0; ksl < 8; ++ksl) {
            s16x8 afr = *(const s16x8*)(&bt[1][lr * 528 + ksl * 64 + lg * 16]);
            s16x8 bfrag = *(const s16x8*)(&Bs[m * 1024 +
                            (((512 + ksl * 64 + lg * 16)) ^ ((m & 7) << 4))]);
            acc = __builtin_amdgcn_mfma_f32_16x16x32_bf16(afr, bfrag, acc, 0, 0, 0);
        }
        // fold this group
#pragma unroll
        for (int e = 0; e < 4; ++e) {
            unsigned oi = (unsigned)(gr0 + g * 16 + lg * 4 + e);
            float val = acc[e] * ahv[e];
            if (oi >= osw) psum1 += val; else psum0 += val;
        }
        acc = (f32x4){0.f, 0.f, 0.f, 0.f};
    }

    // ---- epilogue ------------------------------------------------------------
    psum0 += __shfl_xor(psum0, 16); psum0 += __shfl_xor(psum0, 32);
    psum1 += __shfl_xor(psum1, 16); psum1 += __shfl_xor(psum1, 32);
    if (lane < 16) {
        Pblk[((size_t)b * 2 + 0) * 128 + m] = psum0;
        Pblk[((size_t)b * 2 + 1) * 128 + m] = psum1;
    }
#pragma unroll
    for (int off = 1; off < 64; off <<= 1) {
        sg0 += __shfl_xor(sg0, off); sg1 += __shfl_xor(sg1, off);
        sb0 += __shfl_xor(sb0, off); sb1 += __shfl_xor(sb1, off);
    }
    if (lane == 0) { redS[w] = sg0; redS[8 + w] = sg1; redS[16 + w] = sb0; redS[24 + w] = sb1; }
    __syncthreads();
    if (tid < 2) {
        float S = 0.f, T = 0.f;
#pragma unroll
        for (int k = 0; k < 8; ++k) { S += redS[tid * 8 + k]; T += redS[16 + tid * 8 + k]; }
        SgPart[b * 2 + tid] = S;
        SbPart[b * 2 + tid] = T;
    }
}

// ---------- finalize: col-512 peel + LN fold + bias + relu -------------------
__global__ void finalize_kernel(const float* __restrict__ Pblk, const float* __restrict__ SgPart,
                                const float* __restrict__ SbPart, const float* __restrict__ w5g,
                                const float* __restrict__ w5b, const float* __restrict__ ahT,
                                const float* __restrict__ vh512, const float* __restrict__ mu,
                                const float* __restrict__ rsig, const float* __restrict__ bias,
                                float* __restrict__ out) {
    __shared__ float wg[HP], wb[HP];
    int o = blockIdx.x, m = threadIdx.x;   // 128 threads
    for (int i = m; i < HP; i += 128) {
        wg[i] = w5g[(size_t)o * HP + i];
        wb[i] = w5b[(size_t)o * HP + i];
    }
    __syncthreads();
    float Pf = 0.f, Sgf = 0.f, Sbf = 0.f;
    for (int i = 0; i < HP; ++i) {
        float g = wg[i];
        Pf = fmaf(ahT[(size_t)i * 128 + m], g, Pf);
        Sgf += g; Sbf += wb[i];
    }
    int b0 = (o * HP) >> 7, b1 = (o * HP + 512) >> 7;
    float P = 0.f, Sg = 0.f, Sb = 0.f;
    for (int bb = b0; bb <= b1; ++bb) {
        unsigned of = ((unsigned)bb * 128u) / 513u;
        int sl = o - (int)of;
        if (sl < 0 || sl > 1) continue;
        P  += Pblk[((size_t)bb * 2 + sl) * 128 + m];
        Sg += SgPart[bb * 2 + sl];
        Sb += SbPart[bb * 2 + sl];
    }
    P += vh512[m] * Pf;
    Sg += Sgf;
    Sb += Sbf;
    float x = rsig[m] * (P - mu[m] * Sg) + Sb + bias[o];
    out[m * OD + o] = fmaxf(x, 0.f);
}

extern "C" void kernel_launch(void* const* d_in, const int* in_sizes, int n_in,
                              void* d_out, int out_size, void* d_ws, size_t ws_size,
                              hipStream_t stream) {
    const float* a     = (const float*)d_in[0];
    const float* v     = (const float*)d_in[1];
    const float* gamma = (const float*)d_in[2];
    const float* beta  = (const float*)d_in[3];
    const float* W     = (const float*)d_in[4];
    const float* bias  = (const float*)d_in[5];
    float* out = (float*)d_out;

    float* cur = (float*)d_ws;
    float* mu     = cur; cur += 128;
    float* rsig   = cur; cur += 128;
    float* SgPart = cur; cur += NBLK * 2;               // 2052
    float* SbPart = cur; cur += NBLK * 2;               // 2052
    float* Pblk   = cur; cur += (size_t)NBLK * 2 * 128; // 262656
    float* ahT    = cur; cur += (size_t)HP * 128;       // 65664
    float* vh512  = cur; cur += 128;
    float* w5g    = cur; cur += (size_t)NBLK * 128;     // 131328
    float* w5b    = cur; cur += (size_t)NBLK * 128;     // 131328
    unsigned short* gpb = (unsigned short*)cur;          // 513*512
    unsigned short* bpb = gpb + (size_t)HP * 512;
    unsigned short* vhT = bpb + (size_t)HP * 512;        // 128*512

    prep_all<<<HP + 128 + 1 + 257, 256, 0, stream>>>(a, v, gamma, beta, gpb, bpb, vhT, vh512, ahT);
    prep_w5<<<HP, 256, 0, stream>>>(W, gamma, beta, w5g, w5b);
    stats_kernel<<<128, 256, 0, stream>>>(a, v, mu, rsig);
    stage_fused<<<NBLK, 512, 0, stream>>>(W, gpb, bpb, vhT, ahT, Pblk, SgPart, SbPart);
    finalize_kernel<<<OD, 128, 0, stream>>>(Pblk, SgPart, SbPart, w5g, w5b, ahT, vh512,
                                            mu, rsig, bias, out);
}

// Round 13
// 105.805 us; speedup vs baseline: 2.4717x; 1.3134x over previous
//
#include <hip/hip_runtime.h>
#include <hip/hip_bf16.h>

#define HID 512
#define OD  256
#define HP  513
#define EPSV 1e-5f

typedef float f32x16 __attribute__((ext_vector_type(16)));
typedef short s16x8  __attribute__((ext_vector_type(8)));

static __device__ __forceinline__ unsigned short f2bf(float f) {
    union { float f; unsigned u; } x; x.f = f;
    unsigned r = x.u + 0x7FFFu + ((x.u >> 16) & 1u);   // RNE
    return (unsigned short)(r >> 16);
}
static __device__ __forceinline__ unsigned pkbf(float x, float y) {
    float2 t; t.x = x; t.y = y;
    __hip_bfloat162 h = __float22bfloat162_rn(t);
    union { __hip_bfloat162 h; unsigned u; } c; c.h = h;
    return c.u;
}
static __device__ __forceinline__ float bfu(unsigned short u) {
    union { unsigned q; float f; } cv; cv.q = ((unsigned)u) << 16;
    return cv.f;
}

// permuted k-storage: within a 256-col half, storage s=(ll*8+c) holds true col
// j = c*32+ll. Applied identically to gpb/bpb/vhT -> MFMA pairing consistent.

// ---------- prep: gpb/bpb (bf16, permuted), vhT (bf16, permuted), vh512, ahT -
__global__ void prep_all(const float* __restrict__ a, const float* __restrict__ v,
                         const float* __restrict__ gamma, const float* __restrict__ beta,
                         unsigned short* __restrict__ gpb, unsigned short* __restrict__ bpb,
                         unsigned short* __restrict__ vhT, float* __restrict__ vh512,
                         float* __restrict__ ahT) {
    int b = blockIdx.x, t = threadIdx.x;
    if (b < HP) {
        int ii = b;
        for (int s = t; s < 512; s += 256) {
            int half = s >> 8, ss = s & 255, ll = ss >> 3, c = ss & 7;
            int j = half * 256 + c * 32 + ll;
            gpb[(size_t)ii * 512 + s] = f2bf(gamma[(size_t)ii * HP + j]);
            bpb[(size_t)ii * 512 + s] = f2bf(beta [(size_t)ii * HP + j]);
        }
    } else if (b < HP + 128) {
        int m = b - HP;
        for (int s = t; s < 512; s += 256) {
            int half = s >> 8, ss = s & 255, ll = ss >> 3, c = ss & 7;
            int j = half * 256 + c * 32 + ll;
            float val = (j == 0) ? 1.f : v[m * HID + j - 1];
            vhT[(size_t)m * 512 + s] = f2bf(val);
        }
    } else if (b == HP + 128) {
        if (t < 128) vh512[t] = v[t * HID + 511];
    } else {
        int idx = (b - HP - 129) * 256 + t;
        if (idx < HP * 128) {
            int i = idx >> 7, m = idx & 127;
            ahT[idx] = (i == 0) ? 1.f : a[m * HID + i - 1];
        }
    }
}

// ---------- prep2: gather col-512 of W, pre-scaled by gamma/beta -------------
__global__ void prep_w5(const float* __restrict__ W, const float* __restrict__ gamma,
                        const float* __restrict__ beta,
                        float* __restrict__ w5g, float* __restrict__ w5b) {
    int oi = blockIdx.x * 256 + threadIdx.x;
    if (oi < OD * HP) {
        unsigned ii = (unsigned)oi % 513u;
        float wv = W[(size_t)oi * 513u + 512u];
        w5g[oi] = gamma[(size_t)ii * HP + 512] * wv;
        w5b[oi] = beta [(size_t)ii * HP + 512] * wv;
    }
}

// ---------- stats ------------------------------------------------------------
__global__ void stats_kernel(const float* __restrict__ a, const float* __restrict__ v,
                             float* __restrict__ mu, float* __restrict__ rsig) {
    __shared__ float s1[256], s2[256], s3[256], s4[256];
    int m = blockIdx.x, t = threadIdx.x;
    float a0 = a[m * HID + t], a1 = a[m * HID + t + 256];
    float v0 = v[m * HID + t], v1 = v[m * HID + t + 256];
    s1[t] = a0 + a1; s2[t] = a0 * a0 + a1 * a1;
    s3[t] = v0 + v1; s4[t] = v0 * v0 + v1 * v1;
    __syncthreads();
    for (int off = 128; off > 0; off >>= 1) {
        if (t < off) { s1[t] += s1[t + off]; s2[t] += s2[t + off];
                       s3[t] += s3[t + off]; s4[t] += s4[t + off]; }
        __syncthreads();
    }
    if (t == 0) {
        float Sa = 1.f + s1[0], Qa = 1.f + s2[0];
        float Sv = 1.f + s3[0], Qv = 1.f + s4[0];
        float muv = Sa * Sv / (float)((float)HP * (float)HP);
        float var = Qa * Qv / (float)((float)HP * (float)HP) - muv * muv;
        mu[m]   = muv;
        rsig[m] = rsqrtf(var + EPSV);
    }
}

// ---------- stage: block o owns rows o*513+i, i<512; 32x32x16 MFMA -----------
// 16 groups x 32 rows; per body (group, k-half): conv 2 rows/thread -> A-tile
// (swizzled dbuf), lgkmcnt-only barrier, 8 MFMA/wave (waves: 4 col-chunks x
// 2 ksl-halves). Rolled loop, named prefetch sets. Row i=512 -> finalize.
__global__ __launch_bounds__(512, 2) void stage_fused(
        const float* __restrict__ W, const unsigned short* __restrict__ gpb,
        const unsigned short* __restrict__ bpb, const unsigned short* __restrict__ vhT,
        const float* __restrict__ ahT,
        float* __restrict__ Pout, float* __restrict__ Sgo, float* __restrict__ Sbo) {
    __shared__ __align__(16) char Bs[131072];      // [128 cols][1024B], swz (m&15)<<4
    __shared__ __align__(16) char bt[2][16384];    // A dbuf: [32 rows][512B], swz (r&15)<<4

    const int tid = threadIdx.x, lane = tid & 63, w = tid >> 6;
    const int l31 = lane & 31, kg = lane >> 5;
    const int cr = 2 * w + kg;                 // conv row 0..15 (pairs with cr+16)
    const int colm = (w & 3) * 32 + l31;       // wave's output col
    const int kslb = (w >> 2) * 8;             // wave's ksl range
    const int o = blockIdx.x;
    const unsigned rbase = (unsigned)o * 513u;

    // ---- fill B (swizzled), chunked ----------------------------------------
#pragma unroll
    for (int q0 = 0; q0 < 16; q0 += 4) {
        uint4 vals[4];
#pragma unroll
        for (int qq = 0; qq < 4; ++qq) {
            int idx = tid + (q0 + qq) * 512;
            int mr = idx >> 6, c = idx & 63;
            vals[qq] = *(const uint4*)(vhT + (size_t)mr * 512 + c * 8);
        }
#pragma unroll
        for (int qq = 0; qq < 4; ++qq) {
            int idx = tid + (q0 + qq) * 512;
            int mr = idx >> 6, c = idx & 63;
            *(uint4*)(&Bs[mr * 1024 + ((c * 16) ^ ((mr & 15) << 4))]) = vals[qq];
        }
    }

    float WrA[16], WrB[16];
    uint4 gaA1, gaA2, gaB1, gaB2;
    float ahv[16];
    f32x16 acc;
#pragma unroll
    for (int e = 0; e < 16; ++e) acc[e] = 0.f;
    float psum = 0.f, sg = 0.f, sb = 0.f;

    auto LOADW = [&](int g, int half, float (&dst)[16]) {
        const float* p1 = W + (size_t)(rbase + (unsigned)(g * 32 + cr)) * 513u + half * 256 + l31;
        const float* p2 = p1 + 16 * 513;
#pragma unroll
        for (int c = 0; c < 8; ++c) { dst[c] = p1[c * 32]; dst[8 + c] = p2[c * 32]; }
    };
    auto LOADG = [&](int g, int half, uint4& u1, uint4& u2) {
        u1 = *(const uint4*)(gpb + ((size_t)(g * 32 + cr) << 9) + half * 256 + l31 * 8);
        u2 = *(const uint4*)(gpb + ((size_t)(g * 32 + cr + 16) << 9) + half * 256 + l31 * 8);
    };
    auto CONVROW = [&](const float* Wc, const uint4 gc, const uint4 b4, int row, char* tile) {
        const unsigned gw[4] = {gc.x, gc.y, gc.z, gc.w};
        const unsigned bw[4] = {b4.x, b4.y, b4.z, b4.w};
        float p[8];
        float s = 0.f, t2 = 0.f;
#pragma unroll
        for (int e = 0; e < 8; ++e) {
            unsigned ug = (e & 1) ? (gw[e >> 1] >> 16) : (gw[e >> 1] & 0xffffu);
            unsigned ub = (e & 1) ? (bw[e >> 1] >> 16) : (bw[e >> 1] & 0xffffu);
            p[e] = bfu((unsigned short)ug) * Wc[e];
            s += p[e];
            t2 = fmaf(bfu((unsigned short)ub), Wc[e], t2);
        }
        uint4 o4;
        o4.x = pkbf(p[0], p[1]); o4.y = pkbf(p[2], p[3]);
        o4.z = pkbf(p[4], p[5]); o4.w = pkbf(p[6], p[7]);
        *(uint4*)(tile + row * 512 + ((l31 * 16) ^ ((row & 15) << 4))) = o4;
        sg += s; sb += t2;
    };

    // prologue
    LOADW(0, 0, WrA); LOADG(0, 0, gaA1, gaA2);
    __syncthreads();   // B-fill visible (one-time vmcnt drain)

#pragma unroll 1
    for (int g = 0; g < 16; ++g) {
        // ================= half 0 =================
        uint4 bb1 = *(const uint4*)(bpb + ((size_t)(g * 32 + cr) << 9) + l31 * 8);
        uint4 bb2 = *(const uint4*)(bpb + ((size_t)(g * 32 + cr + 16) << 9) + l31 * 8);
        LOADW(g, 1, WrB); LOADG(g, 1, gaB1, gaB2);
        CONVROW(&WrA[0], gaA1, bb1, cr,      bt[0]);
        CONVROW(&WrA[8], gaA2, bb2, cr + 16, bt[0]);

        __builtin_amdgcn_sched_barrier(0);
        asm volatile("s_waitcnt lgkmcnt(0)" ::: "memory");
        __builtin_amdgcn_s_barrier();
        __builtin_amdgcn_sched_barrier(0);

#pragma unroll
        for (int i2 = 0; i2 < 8; ++i2) {
            int ksl = kslb + i2;
            s16x8 afr = *(const s16x8*)(&bt[0][l31 * 512 +
                          ((ksl * 32 + kg * 16) ^ ((l31 & 15) << 4))]);
            s16x8 bfr = *(const s16x8*)(&Bs[colm * 1024 +
                          ((ksl * 32 + kg * 16) ^ ((colm & 15) << 4))]);
            acc = __builtin_amdgcn_mfma_f32_32x32x16_bf16(afr, bfr, acc, 0, 0, 0);
        }

        // ================= half 1 =================
        uint4 cb1 = *(const uint4*)(bpb + ((size_t)(g * 32 + cr) << 9) + 256 + l31 * 8);
        uint4 cb2 = *(const uint4*)(bpb + ((size_t)(g * 32 + cr + 16) << 9) + 256 + l31 * 8);
        if (g < 15) { LOADW(g + 1, 0, WrA); LOADG(g + 1, 0, gaA1, gaA2); }
#pragma unroll
        for (int e = 0; e < 16; ++e) {
            int row32 = (e & 3) + 8 * (e >> 2) + 4 * kg;
            ahv[e] = ahT[(size_t)(g * 32 + row32) * 128 + colm];
        }
        CONVROW(&WrB[0], gaB1, cb1, cr,      bt[1]);
        CONVROW(&WrB[8], gaB2, cb2, cr + 16, bt[1]);

        __builtin_amdgcn_sched_barrier(0);
        asm volatile("s_waitcnt lgkmcnt(0)" ::: "memory");
        __builtin_amdgcn_s_barrier();
        __builtin_amdgcn_sched_barrier(0);

#pragma unroll
        for (int i2 = 0; i2 < 8; ++i2) {
            int ksl = kslb + i2;
            s16x8 afr = *(const s16x8*)(&bt[1][l31 * 512 +
                          ((ksl * 32 + kg * 16) ^ ((l31 & 15) << 4))]);
            s16x8 bfr = *(const s16x8*)(&Bs[colm * 1024 +
                          ((512 + ksl * 32 + kg * 16) ^ ((colm & 15) << 4))]);
            acc = __builtin_amdgcn_mfma_f32_32x32x16_bf16(afr, bfr, acc, 0, 0, 0);
        }
        // fold this group (C/D: col=lane&31, row=(e&3)+8*(e>>2)+4*(lane>>5))
#pragma unroll
        for (int e = 0; e < 16; ++e) psum = fmaf(acc[e], ahv[e], psum);
#pragma unroll
        for (int e = 0; e < 16; ++e) acc[e] = 0.f;
    }

    // ---- epilogue (reuse Bs as scratch after all reads done) ---------------
    __syncthreads();
    float* redP  = (float*)Bs;          // [128 cols][2 wave-pairs]
    float* redSg = redP + 256;
    float* redSb = redP + 264;
    psum += __shfl_xor(psum, 32);
#pragma unroll
    for (int off = 1; off < 64; off <<= 1) {
        sg += __shfl_xor(sg, off); sb += __shfl_xor(sb, off);
    }
    if (lane < 32) redP[colm * 2 + (w >> 2)] = psum;
    if (lane == 0) { redSg[w] = sg; redSb[w] = sb; }
    __syncthreads();
    if (tid < 128) Pout[(size_t)o * 128 + tid] = redP[tid * 2] + redP[tid * 2 + 1];
    if (tid == 0) {
        float S = 0.f, T = 0.f;
#pragma unroll
        for (int k = 0; k < 8; ++k) { S += redSg[k]; T += redSb[k]; }
        Sgo[o] = S; Sbo[o] = T;
    }
}

// ---------- finalize: i=512 row + j=512 col peels + LN fold + bias + relu ----
__global__ void finalize_kernel(const float* __restrict__ Pout, const float* __restrict__ Sgo,
                                const float* __restrict__ Sbo, const float* __restrict__ w5g,
                                const float* __restrict__ w5b, const float* __restrict__ ahT,
                                const float* __restrict__ vh512, const unsigned short* __restrict__ vhT,
                                const float* __restrict__ W, const float* __restrict__ gamma,
                                const float* __restrict__ beta, const float* __restrict__ mu,
                                const float* __restrict__ rsig, const float* __restrict__ bias,
                                float* __restrict__ out) {
    __shared__ float wg[HP], wb[HP], gws[512], bws[512];
    int o = blockIdx.x, m = threadIdx.x;   // 128 threads
    for (int i = m; i < HP; i += 128) {
        wg[i] = w5g[(size_t)o * HP + i];
        wb[i] = w5b[(size_t)o * HP + i];
    }
    // row i=512, j<512: gamma*W and beta*W in permuted slot order
    for (int j = m; j < 512; j += 128) {
        float wv = W[((size_t)o * 513u + 512u) * 513u + j];
        int s = ((j >> 8) << 8) + ((j & 31) << 3) + ((j & 255) >> 5);
        gws[s] = gamma[(size_t)512 * HP + j] * wv;
        bws[s] = beta [(size_t)512 * HP + j] * wv;
    }
    __syncthreads();
    float Pf = 0.f, Sgf = 0.f, Sbf = 0.f;
    for (int i = 0; i < HP; ++i) {
        float g = wg[i];
        Pf = fmaf(ahT[(size_t)i * 128 + m], g, Pf);
        Sgf += g; Sbf += wb[i];
    }
    float dot = 0.f, Sg2 = 0.f, Sb2 = 0.f;
    const unsigned short* vr = vhT + (size_t)m * 512;
    for (int s = 0; s < 512; ++s) {
        float g = gws[s];
        dot = fmaf(bfu(vr[s]), g, dot);
        Sg2 += g; Sb2 += bws[s];
    }
    float P  = Pout[(size_t)o * 128 + m] + vh512[m] * Pf + ahT[(size_t)512 * 128 + m] * dot;
    float Sg = Sgo[o] + Sgf + Sg2;
    float Sb = Sbo[o] + Sbf + Sb2;
    float x = rsig[m] * (P - mu[m] * Sg) + Sb + bias[o];
    out[m * OD + o] = fmaxf(x, 0.f);
}

extern "C" void kernel_launch(void* const* d_in, const int* in_sizes, int n_in,
                              void* d_out, int out_size, void* d_ws, size_t ws_size,
                              hipStream_t stream) {
    const float* a     = (const float*)d_in[0];
    const float* v     = (const float*)d_in[1];
    const float* gamma = (const float*)d_in[2];
    const float* beta  = (const float*)d_in[3];
    const float* W     = (const float*)d_in[4];
    const float* bias  = (const float*)d_in[5];
    float* out = (float*)d_out;

    float* cur = (float*)d_ws;
    float* mu    = cur; cur += 128;
    float* rsig  = cur; cur += 128;
    float* Sgo   = cur; cur += 256;
    float* Sbo   = cur; cur += 256;
    float* Pout  = cur; cur += (size_t)OD * 128;        // 32768
    float* ahT   = cur; cur += (size_t)HP * 128;        // 65664
    float* vh512 = cur; cur += 128;
    float* w5g   = cur; cur += (size_t)OD * HP;         // 131328
    float* w5b   = cur; cur += (size_t)OD * HP;         // 131328
    unsigned short* gpb = (unsigned short*)cur;          // 513*512
    unsigned short* bpb = gpb + (size_t)HP * 512;
    unsigned short* vhT = bpb + (size_t)HP * 512;        // 128*512

    prep_all<<<HP + 128 + 1 + 257, 256, 0, stream>>>(a, v, gamma, beta, gpb, bpb, vhT, vh512, ahT);
    prep_w5<<<HP, 256, 0, stream>>>(W, gamma, beta, w5g, w5b);
    stats_kernel<<<128, 256, 0, stream>>>(a, v, mu, rsig);
    stage_fused<<<OD, 512, 0, stream>>>(W, gpb, bpb, vhT, ahT, Pout, Sgo, Sbo);
    finalize_kernel<<<OD, 128, 0, stream>>>(Pout, Sgo, Sbo, w5g, w5b, ahT, vh512, vhT,
                                            W, gamma, beta, mu, rsig, bias, out);
}